// Round 11
// baseline (14.099 us; speedup 1.0000x reference)
//
#include <hip/hip_runtime.h>
#include <math.h>

#define HH 128
#define WW 128
#define TT 8
#define NG 1024
#define PP (HH * WW * TT)      // 131072 pixels
#define NS 8                   // gaussian splits
#define GS 128                 // gaussians per split

// tanh via exp2: tanh(x) = 1 - 2/(exp2(2*log2e*x)+1). ~1e-7 rel err, deterministic.
__device__ __forceinline__ float fast_tanh(float x) {
    float e = __builtin_amdgcn_exp2f(x * 2.885390081777926814f);
    return 1.f - 2.f * __builtin_amdgcn_rcpf(e + 1.f);
}

// ---------------------------------------------------------------------------
// Single fused kernel, max-occupancy variant.
// Block = 1024 threads = 16 waves; covers 2 rows (r = t*128 + y).
// Gaussians split 8 ways (128 each) for wave-parallelism:
//   wave w: split s = w>>1, row = w&1; each lane owns pixels (row, lane) and
//   (row, lane+64) -- both share the same per-row {B,C}, halving LDS reads.
// Stage A (barrier-free): wave scans 64 gaussians [128s + 64(row), +64) in ONE
//   ballot round; survivors compacted wave-locally into fixed region
//   sidx[s][64*sub + pos]. Cheap conservative cull: min over continuous (x,t)
//   of sigma at fixed y is dy^2/(2*Sigma_yy); Sigma_yy = c1^2+c3^2 from raw
//   cholesky; keep iff dmin^2 < 32*Sigma_yy (sigma<16, e^-16 ~ 1.1e-7).
// Stage B: threads [128s, 128s+128) do full setup for split s's S_s survivors
//   (ascending gaussian index) -> recs[s].
// Stage C: wave blends its split's survivors for its 128 px (2 px/lane).
// Merge: splits 1..7 park float4 partials; split-0 waves add in ascending
//   split order (deterministic), clip, write out [3][H][W][T].
// ---------------------------------------------------------------------------
__global__ __launch_bounds__(1024, 8) void gv_fused(
    const float* __restrict__ xyz,
    const float* __restrict__ chol,
    const float* __restrict__ feat,
    const float* __restrict__ opac,
    float* __restrict__ out)
{
    __shared__ __align__(16) float recs[NS][GS * 8];   // 32 KB survivor records
    __shared__ int sidx[NS][GS];                       // 4 KB survivor indices
    __shared__ int cnt_lds[16];
    __shared__ __align__(16) float4 pbuf[7][2][WW];    // 28 KB split partials

    const int tid = threadIdx.x;
    const int lane = tid & 63;
    const int wv = tid >> 6;                 // 0..15
    const int s = wv >> 1;                   // split 0..7
    const int sub = wv & 1;                  // row within block / 64-seg in split
    const int r0 = blockIdx.x * 2;           // rows r0, r0+1 (same t)
    const float y0f = (float)(r0 & 127);
    const float tf  = (float)(r0 >> 7);
    const float kneg = -1.44269504088896340736f;   // -log2(e)

    // ---- stage A: barrier-free cull, 1 ballot round per wave ----
    {
        const int n = s * GS + sub * 64 + lane;
        float vy = xyz[n * 3 + 1];
        float c1 = chol[n * 6 + 1];
        float c3 = chol[n * 6 + 3] + 0.5f;
        float my = fmaf(fast_tanh(vy), 64.f, 63.5f);   // 0.5*((tanh+1)*128-1)
        float syy = fmaf(c1, c1, c3 * c3);             // Sigma_yy
        float d0 = my - y0f;
        float d1 = d0 - 1.f;
        float dmin = fminf(fabsf(d0), fabsf(d1));
        bool keep = dmin * dmin < 32.f * syy;

        unsigned long long mask = __ballot(keep);
        if (keep) {
            int pos = __builtin_amdgcn_mbcnt_hi(
                          (unsigned)(mask >> 32),
                          __builtin_amdgcn_mbcnt_lo((unsigned)mask, 0));
            sidx[s][sub * 64 + pos] = n;
        }
        if (lane == 0) cnt_lds[wv] = (int)__popcll(mask);
    }
    __syncthreads();

    // ---- stage B: full setup for split sb's survivors (1 pass, 128 thr) ----
    {
        const int sb = tid >> 7;             // split this thread serves
        const int tq = tid & 127;
        const int cA = cnt_lds[2 * sb];
        const int Sb = cA + cnt_lds[2 * sb + 1];
        if (tq < Sb) {
            const int n = (tq < cA) ? sidx[sb][tq] : sidx[sb][64 + tq - cA];

            float vx = xyz[n * 3 + 0], vy = xyz[n * 3 + 1], vt = xyz[n * 3 + 2];
            float mx = 0.5f * ((fast_tanh(vx) + 1.f) * (float)WW - 1.f);
            float my = 0.5f * ((fast_tanh(vy) + 1.f) * (float)HH - 1.f);
            float mt = 0.5f * ((fast_tanh(vt) + 1.f) * (float)TT - 1.f);

            float c0 = chol[n * 6 + 0] + 0.5f;
            float c1 = chol[n * 6 + 1];
            float c2 = chol[n * 6 + 2] + 0.5f;
            float c3 = chol[n * 6 + 3] + 0.5f;
            float c4 = chol[n * 6 + 4];
            float c5 = chol[n * 6 + 5] + 0.5f;

            // Sigma = L L^T
            float a  = c0 * c0;
            float b  = c0 * c1;
            float cc = c0 * c2;
            float d  = c1 * c1 + c3 * c3;
            float e  = c1 * c2 + c3 * c4;
            float f  = c2 * c2 + c4 * c4 + c5 * c5;

            // symmetric 3x3 inverse via adjugate
            float A00 = d * f - e * e;
            float A01 = cc * e - b * f;
            float A02 = b * e - cc * d;
            float A11 = a * f - cc * cc;
            float A12 = b * cc - a * e;
            float A22 = a * d - b * b;
            float det = a * A00 + b * A01 + cc * A02;
            float rdet = 1.f / det;
            float Q00 = A00 * rdet, Q01 = A01 * rdet, Q02 = A02 * rdet;
            float Q11 = A11 * rdet, Q12 = A12 * rdet, Q22 = A22 * rdet;

            float qmx = Q00 * mx + Q01 * my + Q02 * mt;
            float qmy = Q01 * mx + Q11 * my + Q12 * mt;
            float qmt = Q02 * mx + Q12 * my + Q22 * mt;
            float cst = 0.5f * (mx * qmx + my * qmy + mt * qmt);

            float G0 = 0.5f * Q00, G1 = 0.5f * Q11, G2 = 0.5f * Q22;
            float G3 = Q01, G4 = Q02, G5 = Q12;
            float G6 = -qmx, G7 = -qmy, G8 = -qmt, G9 = cst;

            // fold t (block-constant), then the block's two rows
            float u  = fmaf(G4, tf, G6);
            float v  = fmaf(G5, tf, G7);
            float w0 = fmaf(fmaf(G2, tf, G8), tf, G9);
            float B0 = fmaf(G3, y0f, u);
            float C0 = fmaf(fmaf(G1, y0f, v), y0f, w0);
            float y1f = y0f + 1.f;
            float B1 = fmaf(G3, y1f, u);
            float C1 = fmaf(fmaf(G1, y1f, v), y1f, w0);

            float op = opac[n];
            float4* l4 = (float4*)recs[sb];
            l4[tq * 2 + 0] = (float4){kneg * G0, op * feat[n * 3 + 0],
                                      op * feat[n * 3 + 1], op * feat[n * 3 + 2]};
            l4[tq * 2 + 1] = (float4){kneg * B0, kneg * C0, kneg * B1, kneg * C1};
        }
    }
    __syncthreads();

    // ---- stage C: blend my split's survivors; 2 px/lane, same row ----
    const int S = cnt_lds[2 * s] + cnt_lds[2 * s + 1];
    const float x1 = (float)lane;
    const float x2 = x1 + 64.f;
    float a0 = 0.f, a1 = 0.f, a2 = 0.f;      // px (row, lane)
    float b0 = 0.f, b1 = 0.f, b2 = 0.f;      // px (row, lane+64)
    const float4* lds4 = (const float4*)recs[s];
    const float* recf = recs[s];

#pragma unroll 4
    for (int m = 0; m < S; ++m) {
        float4 af = lds4[m * 2];                                // {A,f0,f1,f2}
        float2 bc = *(const float2*)&recf[m * 8 + 4 + 2 * sub]; // {B,C} my row
        float s1 = fmaf(fmaf(af.x, x1, bc.x), x1, bc.y);
        float s2 = fmaf(fmaf(af.x, x2, bc.x), x2, bc.y);
        float w1 = __builtin_amdgcn_exp2f(s1);
        float w2 = __builtin_amdgcn_exp2f(s2);
        a0 = fmaf(w1, af.y, a0);
        a1 = fmaf(w1, af.z, a1);
        a2 = fmaf(w1, af.w, a2);
        b0 = fmaf(w2, af.y, b0);
        b1 = fmaf(w2, af.z, b1);
        b2 = fmaf(w2, af.w, b2);
    }

    // ---- merge: splits 1..7 park; split 0 adds in fixed order ----
    if (s != 0) {
        pbuf[s - 1][sub][lane]      = (float4){a0, a1, a2, 0.f};
        pbuf[s - 1][sub][lane + 64] = (float4){b0, b1, b2, 0.f};
    }
    __syncthreads();

    if (s == 0) {
#pragma unroll
        for (int k = 0; k < 7; ++k) {
            float4 p = pbuf[k][sub][lane];
            float4 q = pbuf[k][sub][lane + 64];
            a0 += p.x; a1 += p.y; a2 += p.z;
            b0 += q.x; b1 += q.y; b2 += q.z;
        }

        a0 = fminf(fmaxf(a0, 0.f), 1.f);
        a1 = fminf(fmaxf(a1, 0.f), 1.f);
        a2 = fminf(fmaxf(a2, 0.f), 1.f);
        b0 = fminf(fmaxf(b0, 0.f), 1.f);
        b1 = fminf(fmaxf(b1, 0.f), 1.f);
        b2 = fminf(fmaxf(b2, 0.f), 1.f);

        // layout: [3][H][W][T], base = (y*W + x)*T + t ; second pixel at x+64
        const int r = r0 + sub;
        const int y = r & 127, t = r >> 7;
        const int base_o = (y * WW + lane) * TT + t;
        out[base_o] = a0;
        out[base_o + 64 * TT] = b0;
        out[base_o + PP] = a1;
        out[base_o + PP + 64 * TT] = b1;
        out[base_o + 2 * PP] = a2;
        out[base_o + 2 * PP + 64 * TT] = b2;
    }
}

extern "C" void kernel_launch(void* const* d_in, const int* in_sizes, int n_in,
                              void* d_out, int out_size, void* d_ws, size_t ws_size,
                              hipStream_t stream) {
    const float* xyz  = (const float*)d_in[0];
    const float* chol = (const float*)d_in[1];
    const float* feat = (const float*)d_in[2];
    const float* opac = (const float*)d_in[3];
    float* out = (float*)d_out;

    const int blocks = (TT * HH) / 2;        // 512 blocks, 2 rows each
    gv_fused<<<blocks, 1024, 0, stream>>>(xyz, chol, feat, opac, out);
}

// Round 12
// 13.541 us; speedup vs baseline: 1.0412x; 1.0412x over previous
//
#include <hip/hip_runtime.h>
#include <math.h>

#define HH 128
#define WW 128
#define TT 8
#define NG 1024
#define PP (HH * WW * TT)      // 131072 pixels
#define NSP 8                  // gaussian splits (one wave each)
#define GSP 128                // gaussians per split

// tanh via exp2: tanh(x) = 1 - 2/(exp2(2*log2e*x)+1). ~1e-7 rel err, deterministic.
__device__ __forceinline__ float fast_tanh(float x) {
    float e = __builtin_amdgcn_exp2f(x * 2.885390081777926814f);
    return 1.f - 2.f * __builtin_amdgcn_rcpf(e + 1.f);
}

// ---------------------------------------------------------------------------
// Single fused kernel, fully wave-local. Grid = 1024 blocks (one ROW each:
// r = t*128 + y). Block = 512 threads = 8 waves; wave w owns gaussian split
// [128w, 128w+128) END-TO-END (cull -> setup -> blend), so there are NO
// cross-wave dependencies until the final merge (one barrier total).
// Each lane covers pixels (row, lane) and (row, lane+64).
//
// Stage A (wave-local): 2 ballot rounds over the split; conservative cull:
//   min over continuous (x,t) of sigma at fixed y is dy^2/(2*Sigma_yy);
//   Sigma_yy = c1^2+c3^2 from raw cholesky; keep iff dy^2 < 32*Sigma_yy
//   (sigma<16, e^-16 ~ 1.1e-7). Wave-local running count -> sidx[w] packed
//   ascending.
// Stage B (wave-local): full setup for the S_w survivors; single-row record
//   {kneg*G0, fc0, fc1, fc2, kneg*B, kneg*C, 0, 0} -> recs[w].
// Stage C (wave-local): blend S_w survivors for 128 px (2 px/lane):
//   1 ds_read_b128 + 1 ds_read_b64 + 2 Horner + 2 exp2 + 6 blend FMA / iter.
// Merge: waves 1..7 park float4 partials; ONE barrier; wave 0 adds in
//   ascending split order (deterministic), clips, writes out [3][H][W][T].
// ---------------------------------------------------------------------------
__global__ __launch_bounds__(512, 8) void gv_fused(
    const float* __restrict__ xyz,
    const float* __restrict__ chol,
    const float* __restrict__ feat,
    const float* __restrict__ opac,
    float* __restrict__ out)
{
    __shared__ __align__(16) float recs[NSP][GSP * 8];   // 16 KB records
    __shared__ int sidx[NSP][GSP];                       // 4 KB survivor idx
    __shared__ __align__(16) float4 pbuf[NSP - 1][2 * 64]; // 14 KB partials

    const int tid = threadIdx.x;
    const int lane = tid & 63;
    const int w = tid >> 6;                  // wave = split 0..7
    const int r = blockIdx.x;                // row id = t*128 + y
    const float yf = (float)(r & 127);
    const float tf = (float)(r >> 7);
    const float kneg = -1.44269504088896340736f;   // -log2(e)

    // ---- stage A: wave-local cull of split w (2 ballot rounds) ----
    int cnt = 0;
#pragma unroll
    for (int it = 0; it < 2; ++it) {
        const int n = w * GSP + it * 64 + lane;
        float vy = xyz[n * 3 + 1];
        float c1 = chol[n * 6 + 1];
        float c3 = chol[n * 6 + 3] + 0.5f;
        float my = fmaf(fast_tanh(vy), 64.f, 63.5f);   // 0.5*((tanh+1)*128-1)
        float syy = fmaf(c1, c1, c3 * c3);             // Sigma_yy
        float dy = my - yf;
        bool keep = dy * dy < 32.f * syy;

        unsigned long long mask = __ballot(keep);
        if (keep) {
            int pos = __builtin_amdgcn_mbcnt_hi(
                          (unsigned)(mask >> 32),
                          __builtin_amdgcn_mbcnt_lo((unsigned)mask, 0));
            sidx[w][cnt + pos] = n;
        }
        cnt += (int)__popcll(mask);
    }
    const int S = cnt;                       // wave-uniform

    // ---- stage B: wave-local full setup for survivors ----
    for (int j = lane; j < S; j += 64) {
        const int n = sidx[w][j];

        float vx = xyz[n * 3 + 0], vy = xyz[n * 3 + 1], vt = xyz[n * 3 + 2];
        float mx = 0.5f * ((fast_tanh(vx) + 1.f) * (float)WW - 1.f);
        float my = 0.5f * ((fast_tanh(vy) + 1.f) * (float)HH - 1.f);
        float mt = 0.5f * ((fast_tanh(vt) + 1.f) * (float)TT - 1.f);

        float c0 = chol[n * 6 + 0] + 0.5f;
        float c1 = chol[n * 6 + 1];
        float c2 = chol[n * 6 + 2] + 0.5f;
        float c3 = chol[n * 6 + 3] + 0.5f;
        float c4 = chol[n * 6 + 4];
        float c5 = chol[n * 6 + 5] + 0.5f;

        // Sigma = L L^T
        float a  = c0 * c0;
        float b  = c0 * c1;
        float cc = c0 * c2;
        float d  = c1 * c1 + c3 * c3;
        float e  = c1 * c2 + c3 * c4;
        float f  = c2 * c2 + c4 * c4 + c5 * c5;

        // symmetric 3x3 inverse via adjugate
        float A00 = d * f - e * e;
        float A01 = cc * e - b * f;
        float A02 = b * e - cc * d;
        float A11 = a * f - cc * cc;
        float A12 = b * cc - a * e;
        float A22 = a * d - b * b;
        float det = a * A00 + b * A01 + cc * A02;
        float rdet = 1.f / det;
        float Q00 = A00 * rdet, Q01 = A01 * rdet, Q02 = A02 * rdet;
        float Q11 = A11 * rdet, Q12 = A12 * rdet, Q22 = A22 * rdet;

        float qmx = Q00 * mx + Q01 * my + Q02 * mt;
        float qmy = Q01 * mx + Q11 * my + Q12 * mt;
        float qmt = Q02 * mx + Q12 * my + Q22 * mt;
        float cst = 0.5f * (mx * qmx + my * qmy + mt * qmt);

        float G0 = 0.5f * Q00, G1 = 0.5f * Q11, G2 = 0.5f * Q22;
        float G3 = Q01, G4 = Q02, G5 = Q12;
        float G6 = -qmx, G7 = -qmy, G8 = -qmt, G9 = cst;

        // fold t (block-constant) and the block's single row y
        float u  = fmaf(G4, tf, G6);
        float v  = fmaf(G5, tf, G7);
        float w0 = fmaf(fmaf(G2, tf, G8), tf, G9);
        float B  = fmaf(G3, yf, u);
        float C  = fmaf(fmaf(G1, yf, v), yf, w0);

        float op = opac[n];
        float4* l4 = (float4*)recs[w];
        l4[j * 2 + 0] = (float4){kneg * G0, op * feat[n * 3 + 0],
                                 op * feat[n * 3 + 1], op * feat[n * 3 + 2]};
        l4[j * 2 + 1] = (float4){kneg * B, kneg * C, 0.f, 0.f};
    }
    // no barrier: recs[w]/sidx[w] are produced and consumed by wave w only

    // ---- stage C: blend split w's survivors, 2 px/lane (same row) ----
    const float x1 = (float)lane;
    const float x2 = x1 + 64.f;
    float a0 = 0.f, a1 = 0.f, a2 = 0.f;      // px (row, lane)
    float b0 = 0.f, b1 = 0.f, b2 = 0.f;      // px (row, lane+64)
    const float4* lds4 = (const float4*)recs[w];
    const float* recf = recs[w];

#pragma unroll 4
    for (int m = 0; m < S; ++m) {
        float4 af = lds4[m * 2];                          // {A, f0, f1, f2}
        float2 bc = *(const float2*)&recf[m * 8 + 4];     // {B, C}
        float s1 = fmaf(fmaf(af.x, x1, bc.x), x1, bc.y);
        float s2 = fmaf(fmaf(af.x, x2, bc.x), x2, bc.y);
        float w1 = __builtin_amdgcn_exp2f(s1);
        float w2 = __builtin_amdgcn_exp2f(s2);
        a0 = fmaf(w1, af.y, a0);
        a1 = fmaf(w1, af.z, a1);
        a2 = fmaf(w1, af.w, a2);
        b0 = fmaf(w2, af.y, b0);
        b1 = fmaf(w2, af.z, b1);
        b2 = fmaf(w2, af.w, b2);
    }

    // ---- merge: waves 1..7 park; ONE barrier; wave 0 adds in order ----
    if (w != 0) {
        pbuf[w - 1][lane]      = (float4){a0, a1, a2, 0.f};
        pbuf[w - 1][lane + 64] = (float4){b0, b1, b2, 0.f};
    }
    __syncthreads();

    if (w == 0) {
#pragma unroll
        for (int k = 0; k < NSP - 1; ++k) {
            float4 p = pbuf[k][lane];
            float4 q = pbuf[k][lane + 64];
            a0 += p.x; a1 += p.y; a2 += p.z;
            b0 += q.x; b1 += q.y; b2 += q.z;
        }

        a0 = fminf(fmaxf(a0, 0.f), 1.f);
        a1 = fminf(fmaxf(a1, 0.f), 1.f);
        a2 = fminf(fmaxf(a2, 0.f), 1.f);
        b0 = fminf(fmaxf(b0, 0.f), 1.f);
        b1 = fminf(fmaxf(b1, 0.f), 1.f);
        b2 = fminf(fmaxf(b2, 0.f), 1.f);

        // layout: [3][H][W][T], base = (y*W + x)*T + t ; second pixel at x+64
        const int y = r & 127, t = r >> 7;
        const int base_o = (y * WW + lane) * TT + t;
        out[base_o] = a0;
        out[base_o + 64 * TT] = b0;
        out[base_o + PP] = a1;
        out[base_o + PP + 64 * TT] = b1;
        out[base_o + 2 * PP] = a2;
        out[base_o + 2 * PP + 64 * TT] = b2;
    }
}

extern "C" void kernel_launch(void* const* d_in, const int* in_sizes, int n_in,
                              void* d_out, int out_size, void* d_ws, size_t ws_size,
                              hipStream_t stream) {
    const float* xyz  = (const float*)d_in[0];
    const float* chol = (const float*)d_in[1];
    const float* feat = (const float*)d_in[2];
    const float* opac = (const float*)d_in[3];
    float* out = (float*)d_out;

    const int blocks = TT * HH;              // 1024 blocks, one row each
    gv_fused<<<blocks, 512, 0, stream>>>(xyz, chol, feat, opac, out);
}

// Round 13
// 12.679 us; speedup vs baseline: 1.1120x; 1.0680x over previous
//
#include <hip/hip_runtime.h>
#include <math.h>

#define HH 128
#define WW 128
#define TT 8
#define NG 1024
#define PP (HH * WW * TT)      // 131072 pixels
#define GH 512                 // gaussians per half

// tanh via exp2: tanh(x) = 1 - 2/(exp2(2*log2e*x)+1). ~1e-7 rel err, deterministic.
__device__ __forceinline__ float fast_tanh(float x) {
    float e = __builtin_amdgcn_exp2f(x * 2.885390081777926814f);
    return 1.f - 2.f * __builtin_amdgcn_rcpf(e + 1.f);
}

// ---------------------------------------------------------------------------
// BEST-MEASURED VARIANT (R10, 12.5 us): single fused kernel.
// Block = 512 threads = 8 waves; covers 2 rows (r = t*128 + y).
// Gaussians split in two halves to double wave-parallelism:
//   wave w: half h = w>>2 owns gaussians [512h, 512h+512);
//           combo c = w&3: row c>>1, x-half c&1. One pixel per lane.
// Stage A (barrier-free): within half h, wave-segment i = w&3 scans
//   [512h + 128i, +128) in 2 ballot rounds, wave-local running count.
//   Cheap conservative cull: min over continuous (x,t) of sigma at fixed y
//   is dy^2/(2*Sigma_yy); Sigma_yy = c1^2+c3^2 from raw cholesky;
//   keep iff dmin^2 < 32*Sigma_yy (sigma<16, e^-16 ~ 1.1e-7).
// Stage B: per half, its 256 threads do full setup for the S_h survivors
//   (packed ascending gaussian index) -> recs[h].
// Stage C: each wave blends its half's survivors for its 64 px; half-1
//   waves park partials in LDS; half-0 waves add (fixed order lo+hi),
//   clip, write out [3][H][W][T].
// ---------------------------------------------------------------------------
__global__ __launch_bounds__(512) void gv_fused(
    const float* __restrict__ xyz,
    const float* __restrict__ chol,
    const float* __restrict__ feat,
    const float* __restrict__ opac,
    float* __restrict__ out)
{
    __shared__ __align__(16) float recs[2][GH * 8];  // 32 KB survivor records
    __shared__ int sidx[2][GH];                      // 4 KB survivor indices
    __shared__ int cnt_lds[8];
    __shared__ float pbuf[4][3][64];                 // 3 KB half-1 partials

    const int tid = threadIdx.x;
    const int lane = tid & 63;
    const int wv = tid >> 6;                 // 0..7
    const int h = wv >> 2;                   // gaussian half
    const int seg_i = wv & 3;                // 128-gaussian segment in half
    const int r0 = blockIdx.x * 2;           // rows r0, r0+1 (same t)
    const float y0f = (float)(r0 & 127);
    const float tf  = (float)(r0 >> 7);
    const float kneg = -1.44269504088896340736f;   // -log2(e)

    // ---- stage A: barrier-free cull, wave-local compaction ----
    {
        int cnt = 0;
#pragma unroll
        for (int it = 0; it < 2; ++it) {
            const int n = h * GH + seg_i * 128 + it * 64 + lane;
            float vy = xyz[n * 3 + 1];
            float c1 = chol[n * 6 + 1];
            float c3 = chol[n * 6 + 3] + 0.5f;
            float my = fmaf(fast_tanh(vy), 64.f, 63.5f);   // 0.5*((tanh+1)*128-1)
            float syy = fmaf(c1, c1, c3 * c3);             // Sigma_yy
            float d0 = my - y0f;
            float d1 = d0 - 1.f;
            float dmin = fminf(fabsf(d0), fabsf(d1));
            bool keep = dmin * dmin < 32.f * syy;

            unsigned long long mask = __ballot(keep);
            if (keep) {
                int pos = __builtin_amdgcn_mbcnt_hi(
                              (unsigned)(mask >> 32),
                              __builtin_amdgcn_mbcnt_lo((unsigned)mask, 0));
                sidx[h][seg_i * 128 + cnt + pos] = n;
            }
            cnt += (int)__popcll(mask);
        }
        if (lane == 0) cnt_lds[wv] = cnt;
    }
    __syncthreads();

    const int b0 = cnt_lds[h * 4 + 0], b1 = cnt_lds[h * 4 + 1];
    const int b2 = cnt_lds[h * 4 + 2], b3 = cnt_lds[h * 4 + 3];
    const int off1 = b0, off2 = b0 + b1, off3 = b0 + b1 + b2;
    const int S = off3 + b3;                 // survivors in my half

    // ---- stage B: full setup for my half's survivors, packed ascending ----
    const int tg = tid & 255;                // thread index within half-group
    for (int j = tg; j < S; j += 256) {
        int seg = (j >= off1) + (j >= off2) + (j >= off3);
        int base = seg == 0 ? 0 : (seg == 1 ? off1 : (seg == 2 ? off2 : off3));
        const int n = sidx[h][seg * 128 + (j - base)];

        float vx = xyz[n * 3 + 0], vy = xyz[n * 3 + 1], vt = xyz[n * 3 + 2];
        float mx = 0.5f * ((fast_tanh(vx) + 1.f) * (float)WW - 1.f);
        float my = 0.5f * ((fast_tanh(vy) + 1.f) * (float)HH - 1.f);
        float mt = 0.5f * ((fast_tanh(vt) + 1.f) * (float)TT - 1.f);

        float c0 = chol[n * 6 + 0] + 0.5f;
        float c1 = chol[n * 6 + 1];
        float c2 = chol[n * 6 + 2] + 0.5f;
        float c3 = chol[n * 6 + 3] + 0.5f;
        float c4 = chol[n * 6 + 4];
        float c5 = chol[n * 6 + 5] + 0.5f;

        // Sigma = L L^T
        float a  = c0 * c0;
        float b  = c0 * c1;
        float cc = c0 * c2;
        float d  = c1 * c1 + c3 * c3;
        float e  = c1 * c2 + c3 * c4;
        float f  = c2 * c2 + c4 * c4 + c5 * c5;

        // symmetric 3x3 inverse via adjugate
        float A00 = d * f - e * e;
        float A01 = cc * e - b * f;
        float A02 = b * e - cc * d;
        float A11 = a * f - cc * cc;
        float A12 = b * cc - a * e;
        float A22 = a * d - b * b;
        float det = a * A00 + b * A01 + cc * A02;
        float rdet = 1.f / det;
        float Q00 = A00 * rdet, Q01 = A01 * rdet, Q02 = A02 * rdet;
        float Q11 = A11 * rdet, Q12 = A12 * rdet, Q22 = A22 * rdet;

        float qmx = Q00 * mx + Q01 * my + Q02 * mt;
        float qmy = Q01 * mx + Q11 * my + Q12 * mt;
        float qmt = Q02 * mx + Q12 * my + Q22 * mt;
        float cst = 0.5f * (mx * qmx + my * qmy + mt * qmt);

        float G0 = 0.5f * Q00, G1 = 0.5f * Q11, G2 = 0.5f * Q22;
        float G3 = Q01, G4 = Q02, G5 = Q12;
        float G6 = -qmx, G7 = -qmy, G8 = -qmt, G9 = cst;

        // fold t (block-constant), then the block's two rows
        float u  = fmaf(G4, tf, G6);
        float v  = fmaf(G5, tf, G7);
        float w0 = fmaf(fmaf(G2, tf, G8), tf, G9);
        float B0 = fmaf(G3, y0f, u);
        float C0 = fmaf(fmaf(G1, y0f, v), y0f, w0);
        float y1f = y0f + 1.f;
        float B1 = fmaf(G3, y1f, u);
        float C1 = fmaf(fmaf(G1, y1f, v), y1f, w0);

        float op = opac[n];
        float4* l4 = (float4*)recs[h];
        l4[j * 2 + 0] = (float4){kneg * G0, op * feat[n * 3 + 0],
                                 op * feat[n * 3 + 1], op * feat[n * 3 + 2]};
        l4[j * 2 + 1] = (float4){kneg * B0, kneg * C0, kneg * B1, kneg * C1};
    }
    __syncthreads();

    // ---- stage C: blend my half's survivors for my 64 px ----
    const int combo = wv & 3;
    const int rowi = combo >> 1;
    const int x = (combo & 1) * 64 + lane;
    const float xf = (float)x;
    float a0 = 0.f, a1 = 0.f, a2 = 0.f;
    const float4* lds4 = (const float4*)recs[h];
    const float* recf = recs[h];

#pragma unroll 4
    for (int m = 0; m < S; ++m) {
        float4 af = lds4[m * 2];                                 // {A,f0,f1,f2}
        float2 bc = *(const float2*)&recf[m * 8 + 4 + 2 * rowi]; // {B,C} my row
        float s = fmaf(fmaf(af.x, xf, bc.x), xf, bc.y);
        float w = __builtin_amdgcn_exp2f(s);
        a0 = fmaf(w, af.y, a0);
        a1 = fmaf(w, af.z, a1);
        a2 = fmaf(w, af.w, a2);
    }

    // half-1 parks partials; half-0 merges (fixed order lo+hi), clips, stores
    if (h == 1) {
        pbuf[combo][0][lane] = a0;
        pbuf[combo][1][lane] = a1;
        pbuf[combo][2][lane] = a2;
    }
    __syncthreads();

    if (h == 0) {
        a0 += pbuf[combo][0][lane];
        a1 += pbuf[combo][1][lane];
        a2 += pbuf[combo][2][lane];

        a0 = fminf(fmaxf(a0, 0.f), 1.f);
        a1 = fminf(fmaxf(a1, 0.f), 1.f);
        a2 = fminf(fmaxf(a2, 0.f), 1.f);

        // layout: [3][H][W][T], base = (y*W + x)*T + t
        const int r = r0 + rowi;
        const int y = r & 127, t = r >> 7;
        const int base_o = (y * WW + x) * TT + t;
        out[base_o] = a0;
        out[base_o + PP] = a1;
        out[base_o + 2 * PP] = a2;
    }
}

extern "C" void kernel_launch(void* const* d_in, const int* in_sizes, int n_in,
                              void* d_out, int out_size, void* d_ws, size_t ws_size,
                              hipStream_t stream) {
    const float* xyz  = (const float*)d_in[0];
    const float* chol = (const float*)d_in[1];
    const float* feat = (const float*)d_in[2];
    const float* opac = (const float*)d_in[3];
    float* out = (float*)d_out;

    const int blocks = (TT * HH) / 2;        // 512 blocks, 2 rows each
    gv_fused<<<blocks, 512, 0, stream>>>(xyz, chol, feat, opac, out);
}